// Round 5
// baseline (172.223 us; speedup 1.0000x reference)
//
#include <hip/hip_runtime.h>

// ShiftVarConv2D: out[n,m,y,x] = sum_{di,dj} coded[n,y+di-1,x+dj-1] *
//                 W[(y%8)*8+(x%8), m, di*3+dj] + bias[g*16+m]
// N=128, H=128, SUB=16. Weight depends on (y%8, x%8) only.
//
// Mapping: block = (n, b1=y%8, rh=row-half, mh=m-half); 256 threads =
// 32 col-chunks (c -> x0=4c, one float4 of output) x 8 m. Each thread:
// ONE m, 8 rows -> weights (40 floats) read once from LDS into VGPRs and
// amortized over 32 outputs (R2 re-read them 8x -> LDS-pipe-bound).
// Input halo cols via __shfl from neighbor lane's float4.
// Stores: lanes 0-31 = one full 512B row of one channel -> every 64B line
// written by a single instruction (no partial-line RFO traffic).

#define H 128
#define N_BATCH 128
#define SUB 16

typedef float floatx4 __attribute__((ext_vector_type(4)));

__global__ __launch_bounds__(256, 4) void shiftconv_kernel(
        const float* __restrict__ x,
        const float* __restrict__ w,
        const float* __restrict__ bias,
        float* __restrict__ out) {
    int bid = blockIdx.x;
    int nlo = bid & 7;            // XCD swizzle: same n -> same XCD
    int q   = bid >> 3;
    int mh  = q & 1;
    int rh  = (q >> 1) & 1;
    int b1  = (q >> 2) & 7;
    int n   = ((q >> 5) << 3) | nlo;

    // LDS: [mq(8)][h(2)][40]: 36 weights (j*9 + (dy*3+dj)) + 4 bias. 2560 B.
    __shared__ float ws[8 * 2 * 40];
    {
        int t = threadIdx.x;
        if (t < 64) {             // gather from L2-resident weight array
            int ml = t >> 3, j = t & 7;         // j = b2
            int oc = b1 * 128 + j * 16 + mh * 8 + ml;
            float* dst = ws + (ml * 2 + (j >> 2)) * 40;
            int j4 = j & 3;
#pragma unroll
            for (int i = 0; i < 9; ++i) dst[j4 * 9 + i] = w[oc * 9 + i];
            dst[36 + j4] = bias[oc];
        }
    }
    __syncthreads();

    int c  = threadIdx.x & 31;    // x0 = 4c ; wave lanes 0-31 span a full row
    int mq = threadIdx.x >> 5;    // this thread's m (within mh half)
    int h  = c & 1;               // x0%8 == 4h -> b2 = 4h + j
    int x0 = c << 2;

    // Weights for (mq, h) into registers, once: 10x ds_read_b128.
    float wr[40];
    {
        const float4* wp = (const float4*)(ws + (mq * 2 + h) * 40);
#pragma unroll
        for (int k = 0; k < 10; ++k) {
            float4 v = wp[k];
            wr[4 * k]     = v.x;
            wr[4 * k + 1] = v.y;
            wr[4 * k + 2] = v.z;
            wr[4 * k + 3] = v.w;
        }
    }

    const float* xn = x + (size_t)n * (H * H);
    float* ob = out + ((size_t)(n * SUB + mh * 8 + mq)) * (H * H) + x0;

#pragma unroll
    for (int r = 0; r < 8; ++r) {
        int y = b1 + (rh << 6) + (r << 3);
        float in[3][6];           // in[dy][k] = coded[n, y+dy-1, x0+k-1]
#pragma unroll
        for (int dy = 0; dy < 3; ++dy) {
            int ry = y + dy - 1;
            float4 a = make_float4(0.f, 0.f, 0.f, 0.f);
            if ((unsigned)ry < H)                 // wave-uniform branch
                a = *(const float4*)(xn + ry * H + x0);
            in[dy][1] = a.x; in[dy][2] = a.y; in[dy][3] = a.z; in[dy][4] = a.w;
            float lft = __shfl_up(a.w, 1);        // neighbor lane's col x0-1
            float rgt = __shfl_down(a.x, 1);      // neighbor lane's col x0+4
            in[dy][0] = (c > 0)  ? lft : 0.f;     // c==0 -> image edge
            in[dy][5] = (c < 31) ? rgt : 0.f;     // c==31 -> image edge
        }
        float acc[4];
#pragma unroll
        for (int j = 0; j < 4; ++j) acc[j] = wr[36 + j];   // bias
#pragma unroll
        for (int dy = 0; dy < 3; ++dy)
#pragma unroll
            for (int dj = 0; dj < 3; ++dj)
#pragma unroll
                for (int j = 0; j < 4; ++j)
                    acc[j] = fmaf(in[dy][j + dj], wr[j * 9 + dy * 3 + dj], acc[j]);
        floatx4 v = {acc[0], acc[1], acc[2], acc[3]};
        __builtin_nontemporal_store(v, (floatx4*)(ob + y * H));
    }
}

extern "C" void kernel_launch(void* const* d_in, const int* in_sizes, int n_in,
                              void* d_out, int out_size, void* d_ws, size_t ws_size,
                              hipStream_t stream) {
    const float* coded  = (const float*)d_in[0];
    const float* weight = (const float*)d_in[1];
    const float* bias   = (const float*)d_in[2];
    float* out = (float*)d_out;

    shiftconv_kernel<<<N_BATCH * 8 * 2 * 2, 256, 0, stream>>>(coded, weight, bias, out);
}